// Round 1
// baseline (288.660 us; speedup 1.0000x reference)
//
#include <hip/hip_runtime.h>
#include <hip/hip_bf16.h>

typedef __attribute__((ext_vector_type(8))) short bf16x8;
typedef __attribute__((ext_vector_type(4))) float f32x4;

#define XI_ROW 4128   // N + 2L = 4096 + 32
#define KP     8448   // M * W = 256 * 33, reordered as k' = j*256 + m
#define NB     1024   // B
#define NN     4096   // N
#define DDIM   512    // d

__device__ __forceinline__ unsigned short f2bf(float f) {
  union { float f; unsigned u; } c; c.f = f;
  return (unsigned short)((c.u + 0x7FFFu + ((c.u >> 16) & 1u)) >> 16);
}
__device__ __forceinline__ unsigned pk2bf(float a, float b) {
  return (unsigned)f2bf(a) | ((unsigned)f2bf(b) << 16);
}

// ---------------------------------------------------------------------------
// Kernel 0: xi (256 x 4128 f32) -> xiT (4128 x 256 bf16)
// ---------------------------------------------------------------------------
__global__ __launch_bounds__(256) void k_transpose_xi(
    const float* __restrict__ xi, unsigned short* __restrict__ xiT) {
  __shared__ unsigned short tile[32][33];
  int c0 = blockIdx.x * 32, m0 = blockIdx.y * 32;
  int tx = threadIdx.x & 31, ty = threadIdx.x >> 5;  // 256 threads: ty 0..7
#pragma unroll
  for (int i = 0; i < 4; ++i) {
    int m = m0 + ty + i * 8;
    tile[ty + i * 8][tx] = f2bf(xi[(size_t)m * XI_ROW + c0 + tx]);
  }
  __syncthreads();
#pragma unroll
  for (int i = 0; i < 4; ++i) {
    int c = c0 + ty + i * 8;
    xiT[(size_t)c * 256 + m0 + tx] = tile[tx][ty + i * 8];
  }
}

// ---------------------------------------------------------------------------
// Kernel 1: Gt[b][k'] = sigmoid(weight[m,j,:]·u[b,:] + bias[m,j])
//   rows (M-dim) = k' (8448), cols (N-dim) = b (1024), K = d = 512
//   A = weight rows (gathered by k'), B = u^T consumed b-major (u rows direct)
// ---------------------------------------------------------------------------
#define G1_LDK 40   // 32 + 8 pad; 80B row stride, 16B aligned, 2-way banks
__global__ __launch_bounds__(256) void k_gemm1(
    const float* __restrict__ Wt, const float* __restrict__ Bs,
    const float* __restrict__ U, unsigned short* __restrict__ Gt) {
  __shared__ unsigned short Al[128][G1_LDK];
  __shared__ unsigned short Bl[128][G1_LDK];
  const int r0 = blockIdx.x * 128;   // k' row tile (66 tiles)
  const int b0 = blockIdx.y * 128;   // b tile (8 tiles)
  const int t = threadIdx.x;
  const int lane = t & 63, wid = t >> 6;
  const int wr = wid >> 1, wc = wid & 1;     // 2x2 waves, 64x64 each
  const int rl = lane & 15, kg = lane >> 4;

  f32x4 acc[4][4] = {};

  for (int k0 = 0; k0 < DDIM; k0 += 32) {
    __syncthreads();
#pragma unroll
    for (int i = 0; i < 8; ++i) {
      int p = t + i * 256;              // 2048 float2-pairs
      int row = p >> 4, dd2 = p & 15;   // row 0..127, dd2 0..15
      int rg = r0 + row;
      int m = rg & 255, j = rg >> 8;
      float2 va = *(const float2*)(Wt + ((size_t)(m * 33 + j) * DDIM + k0 + dd2 * 2));
      *(unsigned*)&Al[row][dd2 * 2] = pk2bf(va.x, va.y);
      float2 vb = *(const float2*)(U + ((size_t)(b0 + row) * DDIM + k0 + dd2 * 2));
      *(unsigned*)&Bl[row][dd2 * 2] = pk2bf(vb.x, vb.y);
    }
    __syncthreads();

    bf16x8 af[4], bfv[4];
#pragma unroll
    for (int fm = 0; fm < 4; ++fm)
      af[fm] = *(const bf16x8*)&Al[wr * 64 + fm * 16 + rl][kg * 8];
#pragma unroll
    for (int fn = 0; fn < 4; ++fn)
      bfv[fn] = *(const bf16x8*)&Bl[wc * 64 + fn * 16 + rl][kg * 8];
#pragma unroll
    for (int fm = 0; fm < 4; ++fm)
#pragma unroll
      for (int fn = 0; fn < 4; ++fn)
        acc[fm][fn] = __builtin_amdgcn_mfma_f32_16x16x32_bf16(
            af[fm], bfv[fn], acc[fm][fn], 0, 0, 0);
  }

  // epilogue: sigmoid(acc + bias), write Gt[b][k'] (4 consecutive k' packed)
#pragma unroll
  for (int fm = 0; fm < 4; ++fm) {
    int kbase = r0 + wr * 64 + fm * 16 + kg * 4;
    float bs[4];
#pragma unroll
    for (int r = 0; r < 4; ++r) {
      int kk = kbase + r;
      bs[r] = Bs[(kk & 255) * 33 + (kk >> 8)];
    }
#pragma unroll
    for (int fn = 0; fn < 4; ++fn) {
      int b = b0 + wc * 64 + fn * 16 + rl;
      unsigned short o[4];
#pragma unroll
      for (int r = 0; r < 4; ++r) {
        float x = acc[fm][fn][r] + bs[r];
        o[r] = f2bf(1.0f / (1.0f + __expf(-x)));
      }
      unsigned short* dst = Gt + (size_t)b * KP + kbase;
      *(unsigned*)(dst)     = (unsigned)o[0] | ((unsigned)o[1] << 16);
      *(unsigned*)(dst + 2) = (unsigned)o[2] | ((unsigned)o[3] << 16);
    }
  }
}

// ---------------------------------------------------------------------------
// Kernel 2: out[n][b] = sum_{k'} xiT[n + j][m] * Gt[b][k'],  k' = j*256 + m
//   BM=128 (n) x BN=64 (b), BK=64, grid 32x16 = 512 blocks (2/CU)
// ---------------------------------------------------------------------------
#define G2_LDK 72   // 64 + 8 pad; 144B row stride, 16B aligned, 2-way banks
__global__ __launch_bounds__(256) void k_gemm2(
    const unsigned short* __restrict__ xiT, const unsigned short* __restrict__ Gt,
    float* __restrict__ Out) {
  __shared__ unsigned short Al[128][G2_LDK];
  __shared__ unsigned short Bl[64][G2_LDK];
  const int n0 = blockIdx.x * 128;
  const int b0 = blockIdx.y * 64;
  const int t = threadIdx.x;
  const int lane = t & 63, wid = t >> 6;
  const int wr = wid >> 1, wc = wid & 1;   // 2x2 waves: 64(n) x 32(b) each
  const int rl = lane & 15, kg = lane >> 4;

  f32x4 acc[4][2] = {};

  for (int k0 = 0; k0 < KP; k0 += 64) {
    const int j = k0 >> 8, m0 = k0 & 255;   // fixed within a BK=64 step
    __syncthreads();
    // A-tile: Al[noff][mm] = xiT[n0+j+noff][m0+mm]; 128 rows x 64 bf16 (16B x 8)
#pragma unroll
    for (int i = 0; i < 4; ++i) {
      int c = t + i * 256;                  // 1024 chunks
      int noff = c >> 3, k8 = c & 7;
      const unsigned short* src = xiT + (size_t)(n0 + j + noff) * 256 + m0 + k8 * 8;
      *(bf16x8*)&Al[noff][k8 * 8] = *(const bf16x8*)src;
    }
    // B-tile: Bl[boff][kk] = Gt[b0+boff][k0+kk]; 64 rows x 64 bf16
#pragma unroll
    for (int i = 0; i < 2; ++i) {
      int c = t + i * 256;                  // 512 chunks
      int boff = c >> 3, k8 = c & 7;
      const unsigned short* src = Gt + (size_t)(b0 + boff) * KP + k0 + k8 * 8;
      *(bf16x8*)&Bl[boff][k8 * 8] = *(const bf16x8*)src;
    }
    __syncthreads();

#pragma unroll
    for (int kh = 0; kh < 2; ++kh) {
      bf16x8 af[4], bfv[2];
#pragma unroll
      for (int fm = 0; fm < 4; ++fm)
        af[fm] = *(const bf16x8*)&Al[wr * 64 + fm * 16 + rl][kh * 32 + kg * 8];
#pragma unroll
      for (int fn = 0; fn < 2; ++fn)
        bfv[fn] = *(const bf16x8*)&Bl[wc * 32 + fn * 16 + rl][kh * 32 + kg * 8];
#pragma unroll
      for (int fm = 0; fm < 4; ++fm)
#pragma unroll
        for (int fn = 0; fn < 2; ++fn)
          acc[fm][fn] = __builtin_amdgcn_mfma_f32_16x16x32_bf16(
              af[fm], bfv[fn], acc[fm][fn], 0, 0, 0);
    }
  }

  // epilogue: fp32 out[n][b]
#pragma unroll
  for (int fm = 0; fm < 4; ++fm)
#pragma unroll
    for (int fn = 0; fn < 2; ++fn) {
      int n = n0 + wr * 64 + fm * 16 + kg * 4;
      int b = b0 + wc * 32 + fn * 16 + rl;
#pragma unroll
      for (int r = 0; r < 4; ++r)
        Out[(size_t)(n + r) * NB + b] = acc[fm][fn][r];
    }
}

// ---------------------------------------------------------------------------
extern "C" void kernel_launch(void* const* d_in, const int* in_sizes, int n_in,
                              void* d_out, int out_size, void* d_ws, size_t ws_size,
                              hipStream_t stream) {
  const float* u  = (const float*)d_in[0];   // (1024, 512)
  const float* w  = (const float*)d_in[1];   // (256, 33, 512)
  const float* bs = (const float*)d_in[2];   // (256, 33, 1)
  const float* xi = (const float*)d_in[3];   // (256, 4128)
  float* out = (float*)d_out;                // (4096, 1024) f32

  unsigned short* xiT = (unsigned short*)d_ws;                       // 4128*256*2 = 2,113,536 B
  unsigned short* Gt  = (unsigned short*)((char*)d_ws + 2113536);    // 8448*1024*2 = 17,301,504 B

  k_transpose_xi<<<dim3(129, 8), 256, 0, stream>>>(xi, xiT);
  k_gemm1<<<dim3(66, 8), 256, 0, stream>>>(w, bs, u, Gt);
  k_gemm2<<<dim3(32, 16), 256, 0, stream>>>(xiT, Gt, out);
}

// Round 2
// 175.903 us; speedup vs baseline: 1.6410x; 1.6410x over previous
//
#include <hip/hip_runtime.h>
#include <hip/hip_bf16.h>

typedef __attribute__((ext_vector_type(8))) short bf16x8;
typedef __attribute__((ext_vector_type(4))) float f32x4;
typedef unsigned int u32;
typedef unsigned short u16;

#define XI_ROW 4128   // N + 2L = 4096 + 32
#define KP     8448   // M * W = 256 * 33, reordered as k' = j*256 + m
#define NB     1024   // B
#define NN     4096   // N
#define DDIM   512    // d

__device__ __forceinline__ unsigned short f2bf(float f) {
  union { float f; unsigned u; } c; c.f = f;
  return (unsigned short)((c.u + 0x7FFFu + ((c.u >> 16) & 1u)) >> 16);
}
__device__ __forceinline__ unsigned pk2bf(float a, float b) {
  return (unsigned)f2bf(a) | ((unsigned)f2bf(b) << 16);
}

// async global->LDS, 16B per lane, LDS dest = wave-uniform base + lane*16
__device__ __forceinline__ void gld16(const u16* g, u16* l) {
  __builtin_amdgcn_global_load_lds(
      (const __attribute__((address_space(1))) u32*)(const void*)g,
      (__attribute__((address_space(3))) u32*)(void*)l, 16, 0, 0);
}

// ---------------------------------------------------------------------------
// Kernel 0: xi (256 x 4128 f32) -> xiT (4128 x 256 bf16)
// ---------------------------------------------------------------------------
__global__ __launch_bounds__(256) void k_transpose_xi(
    const float* __restrict__ xi, unsigned short* __restrict__ xiT) {
  __shared__ unsigned short tile[32][33];
  int c0 = blockIdx.x * 32, m0 = blockIdx.y * 32;
  int tx = threadIdx.x & 31, ty = threadIdx.x >> 5;  // 256 threads: ty 0..7
#pragma unroll
  for (int i = 0; i < 4; ++i) {
    int m = m0 + ty + i * 8;
    tile[ty + i * 8][tx] = f2bf(xi[(size_t)m * XI_ROW + c0 + tx]);
  }
  __syncthreads();
#pragma unroll
  for (int i = 0; i < 4; ++i) {
    int c = c0 + ty + i * 8;
    xiT[(size_t)c * 256 + m0 + tx] = tile[tx][ty + i * 8];
  }
}

// ---------------------------------------------------------------------------
// Kernel 1: Gt[b][k'] = sigmoid(weight[m,j,:]·u[b,:] + bias[m,j])
// ---------------------------------------------------------------------------
#define G1_LDK 40   // 32 + 8 pad
__global__ __launch_bounds__(256) void k_gemm1(
    const float* __restrict__ Wt, const float* __restrict__ Bs,
    const float* __restrict__ U, unsigned short* __restrict__ Gt) {
  __shared__ unsigned short Al[128][G1_LDK];
  __shared__ unsigned short Bl[128][G1_LDK];
  const int r0 = blockIdx.x * 128;   // k' row tile (66 tiles)
  const int b0 = blockIdx.y * 128;   // b tile (8 tiles)
  const int t = threadIdx.x;
  const int lane = t & 63, wid = t >> 6;
  const int wr = wid >> 1, wc = wid & 1;     // 2x2 waves, 64x64 each
  const int rl = lane & 15, kg = lane >> 4;

  f32x4 acc[4][4] = {};

  for (int k0 = 0; k0 < DDIM; k0 += 32) {
    __syncthreads();
#pragma unroll
    for (int i = 0; i < 8; ++i) {
      int p = t + i * 256;              // 2048 float2-pairs
      int row = p >> 4, dd2 = p & 15;   // row 0..127, dd2 0..15
      int rg = r0 + row;
      int m = rg & 255, j = rg >> 8;
      float2 va = *(const float2*)(Wt + ((size_t)(m * 33 + j) * DDIM + k0 + dd2 * 2));
      *(unsigned*)&Al[row][dd2 * 2] = pk2bf(va.x, va.y);
      float2 vb = *(const float2*)(U + ((size_t)(b0 + row) * DDIM + k0 + dd2 * 2));
      *(unsigned*)&Bl[row][dd2 * 2] = pk2bf(vb.x, vb.y);
    }
    __syncthreads();

    bf16x8 af[4], bfv[4];
#pragma unroll
    for (int fm = 0; fm < 4; ++fm)
      af[fm] = *(const bf16x8*)&Al[wr * 64 + fm * 16 + rl][kg * 8];
#pragma unroll
    for (int fn = 0; fn < 4; ++fn)
      bfv[fn] = *(const bf16x8*)&Bl[wc * 64 + fn * 16 + rl][kg * 8];
#pragma unroll
    for (int fm = 0; fm < 4; ++fm)
#pragma unroll
      for (int fn = 0; fn < 4; ++fn)
        acc[fm][fn] = __builtin_amdgcn_mfma_f32_16x16x32_bf16(
            af[fm], bfv[fn], acc[fm][fn], 0, 0, 0);
  }

  // epilogue: sigmoid(acc + bias), write Gt[b][k']
#pragma unroll
  for (int fm = 0; fm < 4; ++fm) {
    int kbase = r0 + wr * 64 + fm * 16 + kg * 4;
    float bs[4];
#pragma unroll
    for (int r = 0; r < 4; ++r) {
      int kk = kbase + r;
      bs[r] = Bs[(kk & 255) * 33 + (kk >> 8)];
    }
#pragma unroll
    for (int fn = 0; fn < 4; ++fn) {
      int b = b0 + wc * 64 + fn * 16 + rl;
      unsigned short o[4];
#pragma unroll
      for (int r = 0; r < 4; ++r) {
        float x = acc[fm][fn][r] + bs[r];
        o[r] = f2bf(1.0f / (1.0f + __expf(-x)));
      }
      unsigned short* dst = Gt + (size_t)b * KP + kbase;
      *(unsigned*)(dst)     = (unsigned)o[0] | ((unsigned)o[1] << 16);
      *(unsigned*)(dst + 2) = (unsigned)o[2] | ((unsigned)o[3] << 16);
    }
  }
}

// ---------------------------------------------------------------------------
// Kernel 2: out[n][b] = sum_{k'} xiT[n + j][m] * Gt[b][k'],  k' = j*256 + m
//   BM=128 (n) x BN=64 (b), BK=64, grid 32x16 = 512 blocks
//   dbuf LDS + global_load_lds(16B) + XOR chunk swizzle + 1 barrier/K-step.
//   Swizzle (rule 21, both sides): chunk position p = c ^ (row&7); realized
//   by pre-swizzled per-lane GLOBAL source (LDS dest linear) + same XOR on
//   the ds_read_b128 column.
// ---------------------------------------------------------------------------
__global__ __launch_bounds__(256) void k_gemm2(
    const u16* __restrict__ xiT, const u16* __restrict__ Gt,
    float* __restrict__ Out) {
  __shared__ u16 As[2][128 * 64];   // 16 KB each
  __shared__ u16 Bs[2][64 * 64];    //  8 KB each
  const int n0 = blockIdx.x * 128;
  const int b0 = blockIdx.y * 64;
  const int t = threadIdx.x;
  const int lane = t & 63, wid = t >> 6;
  const int wr = wid >> 1, wc = wid & 1;   // 2x2 waves: 64(n) x 32(b) each
  const int rl = lane & 15, kg = lane >> 4, rl7 = rl & 7;
  const int lr = lane >> 3;                 // staging: row within 8-row group
  const int lc = (lane & 7) ^ (lr & 7);     // staging: swizzled source chunk

  // A element [noff][kk] = xiT_flat[(n0+noff)*256 + k0 + kk]  (k0 = j*256+m0)
  const u16* aSrc = xiT + ((size_t)(n0 + wid * 32 + lr) << 8) + lc * 8;
  const u16* bSrc = Gt + (size_t)(b0 + wid * 16 + lr) * KP + lc * 8;

  f32x4 acc[4][2] = {};

  // prologue: stage tile 0 into buf 0
#pragma unroll
  for (int i = 0; i < 4; ++i)
    gld16(aSrc + i * 2048, &As[0][(wid * 4 + i) * 512]);
#pragma unroll
  for (int i = 0; i < 2; ++i)
    gld16(bSrc + (size_t)i * 8 * KP, &Bs[0][(wid * 2 + i) * 512]);
  __syncthreads();   // drains vmcnt before first use

  for (int ts = 0; ts < 132; ++ts) {
    const int cur = ts & 1;
    // issue next tile's loads first (latency hides under MFMA phase)
    if (ts < 131) {
      const int kn = (ts + 1) * 64;
#pragma unroll
      for (int i = 0; i < 4; ++i)
        gld16(aSrc + kn + i * 2048, &As[cur ^ 1][(wid * 4 + i) * 512]);
#pragma unroll
      for (int i = 0; i < 2; ++i)
        gld16(bSrc + kn + (size_t)i * 8 * KP, &Bs[cur ^ 1][(wid * 2 + i) * 512]);
    }
    const u16* Al = &As[cur][0];
    const u16* Bl = &Bs[cur][0];
#pragma unroll
    for (int kh = 0; kh < 2; ++kh) {
      bf16x8 af[4], bfv[2];
#pragma unroll
      for (int fm = 0; fm < 4; ++fm) {
        int row = wr * 64 + fm * 16 + rl;
        af[fm] = *(const bf16x8*)&Al[row * 64 + (((kh * 4 + kg) ^ rl7) * 8)];
      }
#pragma unroll
      for (int fn = 0; fn < 2; ++fn) {
        int row = wc * 32 + fn * 16 + rl;
        bfv[fn] = *(const bf16x8*)&Bl[row * 64 + (((kh * 4 + kg) ^ rl7) * 8)];
      }
#pragma unroll
      for (int fm = 0; fm < 4; ++fm)
#pragma unroll
        for (int fn = 0; fn < 2; ++fn)
          acc[fm][fn] = __builtin_amdgcn_mfma_f32_16x16x32_bf16(
              af[fm], bfv[fn], acc[fm][fn], 0, 0, 0);
    }
    __syncthreads();   // compiler emits vmcnt(0) lgkmcnt(0) drain here
  }

  // epilogue: fp32 out[n][b]
#pragma unroll
  for (int fm = 0; fm < 4; ++fm)
#pragma unroll
    for (int fn = 0; fn < 2; ++fn) {
      int n = n0 + wr * 64 + fm * 16 + kg * 4;
      int b = b0 + wc * 32 + fn * 16 + rl;
#pragma unroll
      for (int r = 0; r < 4; ++r)
        Out[(size_t)(n + r) * NB + b] = acc[fm][fn][r];
    }
}

// ---------------------------------------------------------------------------
extern "C" void kernel_launch(void* const* d_in, const int* in_sizes, int n_in,
                              void* d_out, int out_size, void* d_ws, size_t ws_size,
                              hipStream_t stream) {
  const float* u  = (const float*)d_in[0];   // (1024, 512)
  const float* w  = (const float*)d_in[1];   // (256, 33, 512)
  const float* bs = (const float*)d_in[2];   // (256, 33, 1)
  const float* xi = (const float*)d_in[3];   // (256, 4128)
  float* out = (float*)d_out;                // (4096, 1024) f32

  unsigned short* xiT = (unsigned short*)d_ws;                       // 2,113,536 B
  unsigned short* Gt  = (unsigned short*)((char*)d_ws + 2113536);    // 17,301,504 B

  k_transpose_xi<<<dim3(129, 8), 256, 0, stream>>>(xi, xiT);
  k_gemm1<<<dim3(66, 8), 256, 0, stream>>>(w, bs, u, Gt);
  k_gemm2<<<dim3(32, 16), 256, 0, stream>>>(xiT, Gt, out);
}

// Round 3
// 140.351 us; speedup vs baseline: 2.0567x; 1.2533x over previous
//
#include <hip/hip_runtime.h>
#include <hip/hip_bf16.h>

typedef __attribute__((ext_vector_type(8))) short bf16x8;
typedef __attribute__((ext_vector_type(4))) float f32x4;
typedef unsigned int u32;
typedef unsigned short u16;

#define XI_ROW 4128   // N + 2L
#define KP     8448   // M * W, k' = j*256 + m
#define NB     1024
#define NN     4096
#define DDIM   512

__device__ __forceinline__ u16 f2bf(float f) {
  union { float f; unsigned u; } c; c.f = f;
  return (u16)((c.u + 0x7FFFu + ((c.u >> 16) & 1u)) >> 16);
}
__device__ __forceinline__ u32 pk2bf(float a, float b) {
  return (u32)f2bf(a) | ((u32)f2bf(b) << 16);
}
__device__ __forceinline__ void gld16(const u16* g, u16* l) {
  __builtin_amdgcn_global_load_lds(
      (const __attribute__((address_space(1))) u32*)(const void*)g,
      (__attribute__((address_space(3))) u32*)(void*)l, 16, 0, 0);
}

// ---------------------------------------------------------------------------
// Pre-convert: weight f32 (m*33+j rows) -> Wbf bf16 (k'=j*256+m rows)
// ---------------------------------------------------------------------------
__global__ __launch_bounds__(128) void k_convW(const float* __restrict__ w,
                                               u16* __restrict__ Wbf) {
  int kp = blockIdx.x;                 // 0..8447
  int m = kp & 255, j = kp >> 8;
  const float4* src = (const float4*)(w + (size_t)(m * 33 + j) * DDIM);
  uint2* dst = (uint2*)(Wbf + (size_t)kp * DDIM);
  float4 v = src[threadIdx.x];
  dst[threadIdx.x] = make_uint2(pk2bf(v.x, v.y), pk2bf(v.z, v.w));
}
__global__ __launch_bounds__(128) void k_convU(const float* __restrict__ u,
                                               u16* __restrict__ Ubf) {
  int b = blockIdx.x;                  // 0..1023
  const float4* src = (const float4*)(u + (size_t)b * DDIM);
  uint2* dst = (uint2*)(Ubf + (size_t)b * DDIM);
  float4 v = src[threadIdx.x];
  dst[threadIdx.x] = make_uint2(pk2bf(v.x, v.y), pk2bf(v.z, v.w));
}

// ---------------------------------------------------------------------------
// xi (256 x 4128 f32) -> xiT (4128 x 256 bf16)
// ---------------------------------------------------------------------------
__global__ __launch_bounds__(256) void k_transpose_xi(
    const float* __restrict__ xi, u16* __restrict__ xiT) {
  __shared__ u16 tile[32][33];
  int c0 = blockIdx.x * 32, m0 = blockIdx.y * 32;
  int tx = threadIdx.x & 31, ty = threadIdx.x >> 5;
#pragma unroll
  for (int i = 0; i < 4; ++i)
    tile[ty + i * 8][tx] = f2bf(xi[(size_t)(m0 + ty + i * 8) * XI_ROW + c0 + tx]);
  __syncthreads();
#pragma unroll
  for (int i = 0; i < 4; ++i)
    xiT[(size_t)(c0 + ty + i * 8) * 256 + m0 + tx] = tile[tx][ty + i * 8];
}

// ---------------------------------------------------------------------------
// Shared pipelined GEMM core: 128x128 tile, 4 waves (2x2), wave 64x64 (4x4
// frags of 16x16x32 bf16), BK=64 double-buffered, global_load_lds(16B) with
// both-sides XOR chunk swizzle, counted vmcnt(8) (T4), setprio (T5).
// A addr = row*AS + k ; B addr = row*BS + k.
// ---------------------------------------------------------------------------
#define WAITVM(N) asm volatile("s_waitcnt vmcnt(" #N ")" ::: "memory")

template<int KSTEPS, int AS, int BS>
__device__ __forceinline__ void gemm_pipeline(
    const u16* __restrict__ aSrc, const u16* __restrict__ bSrc,
    u16* As0, u16* As1, u16* Bl0, u16* Bl1,
    int wid, int wr, int wc, int rl, int kg, int rl7,
    f32x4 (&acc)[4][4]) {

  auto stage = [&](u16* Ab, u16* Bb, int kk) {
#pragma unroll
    for (int i = 0; i < 4; ++i)
      gld16(aSrc + (size_t)i * 8 * AS + kk, &Ab[(wid * 4 + i) * 512]);
#pragma unroll
    for (int i = 0; i < 4; ++i)
      gld16(bSrc + (size_t)i * 8 * BS + kk, &Bb[(wid * 4 + i) * 512]);
  };
  auto compute = [&](const u16* Ab, const u16* Bb) {
#pragma unroll
    for (int kh = 0; kh < 2; ++kh) {
      bf16x8 af[4], bfv[4];
#pragma unroll
      for (int fm = 0; fm < 4; ++fm)
        af[fm] = *(const bf16x8*)&Ab[(wr * 64 + fm * 16 + rl) * 64 +
                                     (((kh * 4 + kg) ^ rl7) * 8)];
#pragma unroll
      for (int fn = 0; fn < 4; ++fn)
        bfv[fn] = *(const bf16x8*)&Bb[(wc * 64 + fn * 16 + rl) * 64 +
                                      (((kh * 4 + kg) ^ rl7) * 8)];
      __builtin_amdgcn_s_setprio(1);
#pragma unroll
      for (int fm = 0; fm < 4; ++fm)
#pragma unroll
        for (int fn = 0; fn < 4; ++fn)
          acc[fm][fn] = __builtin_amdgcn_mfma_f32_16x16x32_bf16(
              af[fm], bfv[fn], acc[fm][fn], 0, 0, 0);
      __builtin_amdgcn_s_setprio(0);
    }
  };

  stage(As0, Bl0, 0);
  WAITVM(0);
  __builtin_amdgcn_s_barrier();
#pragma unroll 1
  for (int ts = 0; ts < KSTEPS - 2; ts += 2) {
    stage(As1, Bl1, (ts + 1) * 64);
    WAITVM(8);                       // oldest 8 (current buf) landed
    __builtin_amdgcn_s_barrier();
    compute(As0, Bl0);
    __builtin_amdgcn_s_barrier();    // all waves done reading buf0
    stage(As0, Bl0, (ts + 2) * 64);
    WAITVM(8);
    __builtin_amdgcn_s_barrier();
    compute(As1, Bl1);
    __builtin_amdgcn_s_barrier();
  }
  // tail: tiles KSTEPS-2 (in buf0), KSTEPS-1 (staged now into buf1)
  stage(As1, Bl1, (KSTEPS - 1) * 64);
  WAITVM(8);
  __builtin_amdgcn_s_barrier();
  compute(As0, Bl0);
  __builtin_amdgcn_s_barrier();
  WAITVM(0);
  __builtin_amdgcn_s_barrier();
  compute(As1, Bl1);
}

// ---------------------------------------------------------------------------
// GEMM1: Gt[b][k'] = sigmoid(Wbf[k',:]·Ubf[b,:] + bias[k'])
// grid (66, 8), K=512 -> 8 steps
// ---------------------------------------------------------------------------
__global__ __launch_bounds__(256) void k_gemm1(
    const u16* __restrict__ Wbf, const u16* __restrict__ Ubf,
    const float* __restrict__ Bsrc, u16* __restrict__ Gt) {
  __shared__ u16 As0[8192], As1[8192], Bl0[8192], Bl1[8192];
  const int r0 = blockIdx.x * 128;
  const int b0 = blockIdx.y * 128;
  const int t = threadIdx.x, lane = t & 63, wid = t >> 6;
  const int wr = wid >> 1, wc = wid & 1;
  const int rl = lane & 15, kg = lane >> 4, rl7 = rl & 7;
  const int lr = lane >> 3, lc = (lane & 7) ^ (lr & 7);
  const u16* aSrc = Wbf + (size_t)(r0 + wid * 32 + lr) * DDIM + lc * 8;
  const u16* bSrc = Ubf + (size_t)(b0 + wid * 32 + lr) * DDIM + lc * 8;

  f32x4 acc[4][4] = {};
  gemm_pipeline<8, DDIM, DDIM>(aSrc, bSrc, As0, As1, Bl0, Bl1,
                               wid, wr, wc, rl, kg, rl7, acc);

#pragma unroll
  for (int fm = 0; fm < 4; ++fm) {
    int kbase = r0 + wr * 64 + fm * 16 + kg * 4;
    float b4[4];
#pragma unroll
    for (int r = 0; r < 4; ++r) {
      int kk = kbase + r;
      b4[r] = Bsrc[(kk & 255) * 33 + (kk >> 8)];
    }
#pragma unroll
    for (int fn = 0; fn < 4; ++fn) {
      int b = b0 + wc * 64 + fn * 16 + rl;
      u16 o[4];
#pragma unroll
      for (int r = 0; r < 4; ++r) {
        float x = acc[fm][fn][r] + b4[r];
        o[r] = f2bf(1.0f / (1.0f + __expf(-x)));
      }
      u16* dst = Gt + (size_t)b * KP + kbase;
      *(u32*)(dst)     = (u32)o[0] | ((u32)o[1] << 16);
      *(u32*)(dst + 2) = (u32)o[2] | ((u32)o[3] << 16);
    }
  }
}

// ---------------------------------------------------------------------------
// GEMM2: out[n][b] = sum_k' xiT_flat[n*256 + k'] * Gt[b][k']
// grid 256 (1/CU), XCD swizzle: b-tile = lid&7 -> one b-tile per XCD
// ---------------------------------------------------------------------------
__global__ __launch_bounds__(256) void k_gemm2(
    const u16* __restrict__ xiT, const u16* __restrict__ Gt,
    float* __restrict__ Out) {
  __shared__ u16 As0[8192], As1[8192], Bl0[8192], Bl1[8192];
  const int lid = blockIdx.x;
  const int n0 = (lid >> 3) * 128;   // 32 n-tiles
  const int b0 = (lid & 7) * 128;    // 8 b-tiles, one per XCD
  const int t = threadIdx.x, lane = t & 63, wid = t >> 6;
  const int wr = wid >> 1, wc = wid & 1;
  const int rl = lane & 15, kg = lane >> 4, rl7 = rl & 7;
  const int lr = lane >> 3, lc = (lane & 7) ^ (lr & 7);
  const u16* aSrc = xiT + (size_t)(n0 + wid * 32 + lr) * 256 + lc * 8;
  const u16* bSrc = Gt + (size_t)(b0 + wid * 32 + lr) * KP + lc * 8;

  f32x4 acc[4][4] = {};
  gemm_pipeline<132, 256, KP>(aSrc, bSrc, As0, As1, Bl0, Bl1,
                              wid, wr, wc, rl, kg, rl7, acc);

#pragma unroll
  for (int fm = 0; fm < 4; ++fm)
#pragma unroll
    for (int fn = 0; fn < 4; ++fn) {
      int n = n0 + wr * 64 + fm * 16 + kg * 4;
      int b = b0 + wc * 64 + fn * 16 + rl;
#pragma unroll
      for (int r = 0; r < 4; ++r)
        Out[(size_t)(n + r) * NB + b] = acc[fm][fn][r];
    }
}

// ---------------------------------------------------------------------------
extern "C" void kernel_launch(void* const* d_in, const int* in_sizes, int n_in,
                              void* d_out, int out_size, void* d_ws, size_t ws_size,
                              hipStream_t stream) {
  const float* u  = (const float*)d_in[0];   // (1024, 512)
  const float* w  = (const float*)d_in[1];   // (256, 33, 512)
  const float* bs = (const float*)d_in[2];   // (256, 33, 1)
  const float* xi = (const float*)d_in[3];   // (256, 4128)
  float* out = (float*)d_out;                // (4096, 1024) f32

  u16* xiT = (u16*)d_ws;                               //  2,113,536 B
  u16* Gt  = (u16*)((char*)d_ws + 2113536);            // 17,301,504 B
  u16* Wbf = (u16*)((char*)d_ws + 19415040);           //  8,650,752 B
  u16* Ubf = (u16*)((char*)d_ws + 28065792);           //  1,048,576 B

  k_convW<<<8448, 128, 0, stream>>>(w, Wbf);
  k_convU<<<1024, 128, 0, stream>>>(u, Ubf);
  k_transpose_xi<<<dim3(129, 8), 256, 0, stream>>>(xi, xiT);
  k_gemm1<<<dim3(66, 8), 256, 0, stream>>>(Wbf, Ubf, bs, Gt);
  k_gemm2<<<256, 256, 0, stream>>>(xiT, Gt, out);
}

// Round 4
// 119.691 us; speedup vs baseline: 2.4117x; 1.1726x over previous
//
#include <hip/hip_runtime.h>
#include <hip/hip_bf16.h>

typedef __attribute__((ext_vector_type(8))) short bf16x8;
typedef __attribute__((ext_vector_type(4))) float f32x4;
typedef unsigned int u32;
typedef unsigned short u16;

#define XI_ROW 4128   // N + 2L
#define KP     8448   // M * W, k' = j*256 + m
#define NB     1024
#define NN     4096
#define DDIM   512
#define KHALF  4224   // KP / 2

__device__ __forceinline__ u16 f2bf(float f) {
  union { float f; unsigned u; } c; c.f = f;
  return (u16)((c.u + 0x7FFFu + ((c.u >> 16) & 1u)) >> 16);
}
__device__ __forceinline__ u32 pk2bf(float a, float b) {
  return (u32)f2bf(a) | ((u32)f2bf(b) << 16);
}
__device__ __forceinline__ void gld16(const u16* g, u16* l) {
  __builtin_amdgcn_global_load_lds(
      (const __attribute__((address_space(1))) u32*)(const void*)g,
      (__attribute__((address_space(3))) u32*)(void*)l, 16, 0, 0);
}

// ---------------------------------------------------------------------------
// Pre-convert: weight f32 (m*33+j rows) -> Wbf bf16 (k'=j*256+m rows)
// ---------------------------------------------------------------------------
__global__ __launch_bounds__(128) void k_convW(const float* __restrict__ w,
                                               u16* __restrict__ Wbf) {
  int kp = blockIdx.x;                 // 0..8447
  int m = kp & 255, j = kp >> 8;
  const float4* src = (const float4*)(w + (size_t)(m * 33 + j) * DDIM);
  uint2* dst = (uint2*)(Wbf + (size_t)kp * DDIM);
  float4 v = src[threadIdx.x];
  dst[threadIdx.x] = make_uint2(pk2bf(v.x, v.y), pk2bf(v.z, v.w));
}
__global__ __launch_bounds__(128) void k_convU(const float* __restrict__ u,
                                               u16* __restrict__ Ubf) {
  int b = blockIdx.x;                  // 0..1023
  const float4* src = (const float4*)(u + (size_t)b * DDIM);
  uint2* dst = (uint2*)(Ubf + (size_t)b * DDIM);
  float4 v = src[threadIdx.x];
  dst[threadIdx.x] = make_uint2(pk2bf(v.x, v.y), pk2bf(v.z, v.w));
}

// ---------------------------------------------------------------------------
// xi (256 x 4128 f32) -> xiT (4128 x 256 bf16)
// ---------------------------------------------------------------------------
__global__ __launch_bounds__(256) void k_transpose_xi(
    const float* __restrict__ xi, u16* __restrict__ xiT) {
  __shared__ u16 tile[32][33];
  int c0 = blockIdx.x * 32, m0 = blockIdx.y * 32;
  int tx = threadIdx.x & 31, ty = threadIdx.x >> 5;
#pragma unroll
  for (int i = 0; i < 4; ++i)
    tile[ty + i * 8][tx] = f2bf(xi[(size_t)(m0 + ty + i * 8) * XI_ROW + c0 + tx]);
  __syncthreads();
#pragma unroll
  for (int i = 0; i < 4; ++i)
    xiT[(size_t)(c0 + ty + i * 8) * 256 + m0 + tx] = tile[tx][ty + i * 8];
}

// ---------------------------------------------------------------------------
// Pipelined GEMM core: 128x128 tile, 4 waves (2x2), wave 64x64 (4x4 frags of
// 16x16x32 bf16), BK=64 dbuf, global_load_lds(16B) with both-sides XOR chunk
// swizzle, counted vmcnt(8) (T4), setprio (T5). A addr = row*AS+k, B = row*BS+k.
// ---------------------------------------------------------------------------
#define WAITVM(N) asm volatile("s_waitcnt vmcnt(" #N ")" ::: "memory")

template<int KSTEPS, int AS, int BS>
__device__ __forceinline__ void gemm_pipeline(
    const u16* __restrict__ aSrc, const u16* __restrict__ bSrc,
    u16* As0, u16* As1, u16* Bl0, u16* Bl1,
    int wid, int wr, int wc, int rl, int kg, int rl7,
    f32x4 (&acc)[4][4]) {

  auto stage = [&](u16* Ab, u16* Bb, int kk) {
#pragma unroll
    for (int i = 0; i < 4; ++i)
      gld16(aSrc + (size_t)i * 8 * AS + kk, &Ab[(wid * 4 + i) * 512]);
#pragma unroll
    for (int i = 0; i < 4; ++i)
      gld16(bSrc + (size_t)i * 8 * BS + kk, &Bb[(wid * 4 + i) * 512]);
  };
  auto compute = [&](const u16* Ab, const u16* Bb) {
#pragma unroll
    for (int kh = 0; kh < 2; ++kh) {
      bf16x8 af[4], bfv[4];
#pragma unroll
      for (int fm = 0; fm < 4; ++fm)
        af[fm] = *(const bf16x8*)&Ab[(wr * 64 + fm * 16 + rl) * 64 +
                                     (((kh * 4 + kg) ^ rl7) * 8)];
#pragma unroll
      for (int fn = 0; fn < 4; ++fn)
        bfv[fn] = *(const bf16x8*)&Bb[(wc * 64 + fn * 16 + rl) * 64 +
                                      (((kh * 4 + kg) ^ rl7) * 8)];
      __builtin_amdgcn_s_setprio(1);
#pragma unroll
      for (int fm = 0; fm < 4; ++fm)
#pragma unroll
        for (int fn = 0; fn < 4; ++fn)
          acc[fm][fn] = __builtin_amdgcn_mfma_f32_16x16x32_bf16(
              af[fm], bfv[fn], acc[fm][fn], 0, 0, 0);
      __builtin_amdgcn_s_setprio(0);
    }
  };

  stage(As0, Bl0, 0);
  WAITVM(0);
  __builtin_amdgcn_s_barrier();
#pragma unroll 1
  for (int ts = 0; ts < KSTEPS - 2; ts += 2) {
    stage(As1, Bl1, (ts + 1) * 64);
    WAITVM(8);
    __builtin_amdgcn_s_barrier();
    compute(As0, Bl0);
    __builtin_amdgcn_s_barrier();
    stage(As0, Bl0, (ts + 2) * 64);
    WAITVM(8);
    __builtin_amdgcn_s_barrier();
    compute(As1, Bl1);
    __builtin_amdgcn_s_barrier();
  }
  stage(As1, Bl1, (KSTEPS - 1) * 64);
  WAITVM(8);
  __builtin_amdgcn_s_barrier();
  compute(As0, Bl0);
  __builtin_amdgcn_s_barrier();
  WAITVM(0);
  __builtin_amdgcn_s_barrier();
  compute(As1, Bl1);
}

// ---------------------------------------------------------------------------
// GEMM1: Gt[b][k'] = sigmoid(Wbf[k',:]·Ubf[b,:] + bias[k'])
// ---------------------------------------------------------------------------
__global__ __launch_bounds__(256) void k_gemm1(
    const u16* __restrict__ Wbf, const u16* __restrict__ Ubf,
    const float* __restrict__ Bsrc, u16* __restrict__ Gt) {
  __shared__ u16 As0[8192], As1[8192], Bl0[8192], Bl1[8192];
  const int r0 = blockIdx.x * 128;
  const int b0 = blockIdx.y * 128;
  const int t = threadIdx.x, lane = t & 63, wid = t >> 6;
  const int wr = wid >> 1, wc = wid & 1;
  const int rl = lane & 15, kg = lane >> 4, rl7 = rl & 7;
  const int lr = lane >> 3, lc = (lane & 7) ^ (lr & 7);
  const u16* aSrc = Wbf + (size_t)(r0 + wid * 32 + lr) * DDIM + lc * 8;
  const u16* bSrc = Ubf + (size_t)(b0 + wid * 32 + lr) * DDIM + lc * 8;

  f32x4 acc[4][4] = {};
  gemm_pipeline<8, DDIM, DDIM>(aSrc, bSrc, As0, As1, Bl0, Bl1,
                               wid, wr, wc, rl, kg, rl7, acc);

#pragma unroll
  for (int fm = 0; fm < 4; ++fm) {
    int kbase = r0 + wr * 64 + fm * 16 + kg * 4;
    float b4[4];
#pragma unroll
    for (int r = 0; r < 4; ++r) {
      int kk = kbase + r;
      b4[r] = Bsrc[(kk & 255) * 33 + (kk >> 8)];
    }
#pragma unroll
    for (int fn = 0; fn < 4; ++fn) {
      int b = b0 + wc * 64 + fn * 16 + rl;
      u16 o[4];
#pragma unroll
      for (int r = 0; r < 4; ++r) {
        float x = acc[fm][fn][r] + b4[r];
        o[r] = f2bf(1.0f / (1.0f + __expf(-x)));
      }
      u16* dst = Gt + (size_t)b * KP + kbase;
      *(u32*)(dst)     = (u32)o[0] | ((u32)o[1] << 16);
      *(u32*)(dst + 2) = (u32)o[2] | ((u32)o[3] << 16);
    }
  }
}

// ---------------------------------------------------------------------------
// GEMM2 (K-split 2): grid 512 = n(32) x ks(2) x b(8); lid&7 = b-tile = XCD.
// ks=0 writes Out, ks=1 writes Part; k_reduce sums.
// ---------------------------------------------------------------------------
__global__ __launch_bounds__(256) void k_gemm2(
    const u16* __restrict__ xiT, const u16* __restrict__ Gt,
    float* __restrict__ Out, float* __restrict__ Part) {
  __shared__ u16 As0[8192], As1[8192], Bl0[8192], Bl1[8192];
  const int lid = blockIdx.x;
  const int b0 = (lid & 7) * 128;        // 8 b-tiles, one per XCD
  const int ks = (lid >> 3) & 1;         // K half
  const int n0 = (lid >> 4) * 128;       // 32 n-tiles
  const int t = threadIdx.x, lane = t & 63, wid = t >> 6;
  const int wr = wid >> 1, wc = wid & 1;
  const int rl = lane & 15, kg = lane >> 4, rl7 = rl & 7;
  const int lr = lane >> 3, lc = (lane & 7) ^ (lr & 7);
  const int kOff = ks * KHALF;
  const u16* aSrc = xiT + (size_t)(n0 + wid * 32 + lr) * 256 + lc * 8 + kOff;
  const u16* bSrc = Gt + (size_t)(b0 + wid * 32 + lr) * KP + lc * 8 + kOff;

  f32x4 acc[4][4] = {};
  gemm_pipeline<66, 256, KP>(aSrc, bSrc, As0, As1, Bl0, Bl1,
                             wid, wr, wc, rl, kg, rl7, acc);

  float* __restrict__ dst = ks ? Part : Out;
#pragma unroll
  for (int fm = 0; fm < 4; ++fm)
#pragma unroll
    for (int fn = 0; fn < 4; ++fn) {
      int n = n0 + wr * 64 + fm * 16 + kg * 4;
      int b = b0 + wc * 64 + fn * 16 + rl;
#pragma unroll
      for (int r = 0; r < 4; ++r)
        dst[(size_t)(n + r) * NB + b] = acc[fm][fn][r];
    }
}

// ---------------------------------------------------------------------------
// Reduce: Out += Part  (4M floats, 1M float4)
// ---------------------------------------------------------------------------
__global__ __launch_bounds__(256) void k_reduce(float* __restrict__ Out,
                                                const float* __restrict__ Part) {
  size_t i = (size_t)blockIdx.x * 256 + threadIdx.x;
  float4 a = ((const float4*)Out)[i];
  float4 p = ((const float4*)Part)[i];
  a.x += p.x; a.y += p.y; a.z += p.z; a.w += p.w;
  ((float4*)Out)[i] = a;
}

// ---------------------------------------------------------------------------
extern "C" void kernel_launch(void* const* d_in, const int* in_sizes, int n_in,
                              void* d_out, int out_size, void* d_ws, size_t ws_size,
                              hipStream_t stream) {
  const float* u  = (const float*)d_in[0];   // (1024, 512)
  const float* w  = (const float*)d_in[1];   // (256, 33, 512)
  const float* bs = (const float*)d_in[2];   // (256, 33, 1)
  const float* xi = (const float*)d_in[3];   // (256, 4128)
  float* out = (float*)d_out;                // (4096, 1024) f32

  u16*   xiT  = (u16*)d_ws;                              //  2,113,536 B
  u16*   Gt   = (u16*)((char*)d_ws + 2113536);           // 17,301,504 B
  u16*   Wbf  = (u16*)((char*)d_ws + 19415040);          //  8,650,752 B
  u16*   Ubf  = (u16*)((char*)d_ws + 28065792);          //  1,048,576 B
  float* Part = (float*)((char*)d_ws + 29114368);        // 16,777,216 B

  k_convW<<<8448, 128, 0, stream>>>(w, Wbf);
  k_convU<<<1024, 128, 0, stream>>>(u, Ubf);
  k_transpose_xi<<<dim3(129, 8), 256, 0, stream>>>(xi, xiT);
  k_gemm1<<<dim3(66, 8), 256, 0, stream>>>(Wbf, Ubf, bs, Gt);
  k_gemm2<<<512, 256, 0, stream>>>(xiT, Gt, out, Part);
  k_reduce<<<4096, 256, 0, stream>>>(out, Part);
}

// Round 5
// 112.454 us; speedup vs baseline: 2.5669x; 1.0644x over previous
//
#include <hip/hip_runtime.h>
#include <hip/hip_bf16.h>

typedef __attribute__((ext_vector_type(8))) short bf16x8;
typedef __attribute__((ext_vector_type(4))) float f32x4;
typedef unsigned int u32;
typedef unsigned short u16;

#define XI_ROW 4128   // N + 2L
#define KP     8448   // M * W, k' = j*256 + m
#define NB     1024
#define NN     4096
#define DDIM   512

__device__ __forceinline__ u16 f2bf(float f) {
  union { float f; unsigned u; } c; c.f = f;
  return (u16)((c.u + 0x7FFFu + ((c.u >> 16) & 1u)) >> 16);
}
__device__ __forceinline__ float bf2f(u16 h) {
  union { u32 u; float f; } c; c.u = ((u32)h) << 16; return c.f;
}
__device__ __forceinline__ u32 pk2bf(float a, float b) {
  return (u32)f2bf(a) | ((u32)f2bf(b) << 16);
}
__device__ __forceinline__ void gld16(const u16* g, u16* l) {
  __builtin_amdgcn_global_load_lds(
      (const __attribute__((address_space(1))) u32*)(const void*)g,
      (__attribute__((address_space(3))) u32*)(void*)l, 16, 0, 0);
}

#define BAR() __builtin_amdgcn_s_barrier()
#define LGKM0() asm volatile("s_waitcnt lgkmcnt(0)" ::: "memory")
#define WAITVM(N) asm volatile("s_waitcnt vmcnt(" #N ")" ::: "memory")

// ---------------------------------------------------------------------------
// Pre-convert: weight f32 (m*33+j rows) -> Wbf bf16 (k'=j*256+m rows)
// ---------------------------------------------------------------------------
__global__ __launch_bounds__(128) void k_convW(const float* __restrict__ w,
                                               u16* __restrict__ Wbf) {
  int kp = blockIdx.x;                 // 0..8447
  int m = kp & 255, j = kp >> 8;
  const float4* src = (const float4*)(w + (size_t)(m * 33 + j) * DDIM);
  uint2* dst = (uint2*)(Wbf + (size_t)kp * DDIM);
  float4 v = src[threadIdx.x];
  dst[threadIdx.x] = make_uint2(pk2bf(v.x, v.y), pk2bf(v.z, v.w));
}
__global__ __launch_bounds__(128) void k_convU(const float* __restrict__ u,
                                               u16* __restrict__ Ubf) {
  int b = blockIdx.x;                  // 0..1023
  const float4* src = (const float4*)(u + (size_t)b * DDIM);
  uint2* dst = (uint2*)(Ubf + (size_t)b * DDIM);
  float4 v = src[threadIdx.x];
  dst[threadIdx.x] = make_uint2(pk2bf(v.x, v.y), pk2bf(v.z, v.w));
}

// ---------------------------------------------------------------------------
// xi (256 x 4128 f32) -> xiT (4128 x 256 bf16)
// ---------------------------------------------------------------------------
__global__ __launch_bounds__(256) void k_transpose_xi(
    const float* __restrict__ xi, u16* __restrict__ xiT) {
  __shared__ u16 tile[32][33];
  int c0 = blockIdx.x * 32, m0 = blockIdx.y * 32;
  int tx = threadIdx.x & 31, ty = threadIdx.x >> 5;
#pragma unroll
  for (int i = 0; i < 4; ++i)
    tile[ty + i * 8][tx] = f2bf(xi[(size_t)(m0 + ty + i * 8) * XI_ROW + c0 + tx]);
  __syncthreads();
#pragma unroll
  for (int i = 0; i < 4; ++i)
    xiT[(size_t)(c0 + ty + i * 8) * 256 + m0 + tx] = tile[tx][ty + i * 8];
}

// ---------------------------------------------------------------------------
// 2-phase pipelined core for GEMM1 (proven): 128x128 tile, 4 waves, BK=64.
// ---------------------------------------------------------------------------
template<int KSTEPS, int AS, int BS>
__device__ __forceinline__ void gemm_pipeline(
    const u16* __restrict__ aSrc, const u16* __restrict__ bSrc,
    u16* As0, u16* As1, u16* Bl0, u16* Bl1,
    int wid, int wr, int wc, int rl, int kg, int rl7,
    f32x4 (&acc)[4][4]) {

  auto stage = [&](u16* Ab, u16* Bb, int kk) {
#pragma unroll
    for (int i = 0; i < 4; ++i)
      gld16(aSrc + (size_t)i * 8 * AS + kk, &Ab[(wid * 4 + i) * 512]);
#pragma unroll
    for (int i = 0; i < 4; ++i)
      gld16(bSrc + (size_t)i * 8 * BS + kk, &Bb[(wid * 4 + i) * 512]);
  };
  auto compute = [&](const u16* Ab, const u16* Bb) {
#pragma unroll
    for (int kh = 0; kh < 2; ++kh) {
      bf16x8 af[4], bfv[4];
#pragma unroll
      for (int fm = 0; fm < 4; ++fm)
        af[fm] = *(const bf16x8*)&Ab[(wr * 64 + fm * 16 + rl) * 64 +
                                     (((kh * 4 + kg) ^ rl7) * 8)];
#pragma unroll
      for (int fn = 0; fn < 4; ++fn)
        bfv[fn] = *(const bf16x8*)&Bb[(wc * 64 + fn * 16 + rl) * 64 +
                                      (((kh * 4 + kg) ^ rl7) * 8)];
      __builtin_amdgcn_s_setprio(1);
#pragma unroll
      for (int fm = 0; fm < 4; ++fm)
#pragma unroll
        for (int fn = 0; fn < 4; ++fn)
          acc[fm][fn] = __builtin_amdgcn_mfma_f32_16x16x32_bf16(
              af[fm], bfv[fn], acc[fm][fn], 0, 0, 0);
      __builtin_amdgcn_s_setprio(0);
    }
  };

  stage(As0, Bl0, 0);
  WAITVM(0);
  BAR();
#pragma unroll 1
  for (int ts = 0; ts < KSTEPS - 2; ts += 2) {
    stage(As1, Bl1, (ts + 1) * 64);
    WAITVM(8);
    BAR();
    compute(As0, Bl0);
    BAR();
    stage(As0, Bl0, (ts + 2) * 64);
    WAITVM(8);
    BAR();
    compute(As1, Bl1);
    BAR();
  }
  stage(As1, Bl1, (KSTEPS - 1) * 64);
  WAITVM(8);
  BAR();
  compute(As0, Bl0);
  BAR();
  WAITVM(0);
  BAR();
  compute(As1, Bl1);
}

// ---------------------------------------------------------------------------
// GEMM1: Gt[b][k'] = sigmoid(Wbf[k',:]·Ubf[b,:] + bias[k'])
// ---------------------------------------------------------------------------
__global__ __launch_bounds__(256) void k_gemm1(
    const u16* __restrict__ Wbf, const u16* __restrict__ Ubf,
    const float* __restrict__ Bsrc, u16* __restrict__ Gt) {
  __shared__ u16 As0[8192], As1[8192], Bl0[8192], Bl1[8192];
  const int r0 = blockIdx.x * 128;
  const int b0 = blockIdx.y * 128;
  const int t = threadIdx.x, lane = t & 63, wid = t >> 6;
  const int wr = wid >> 1, wc = wid & 1;
  const int rl = lane & 15, kg = lane >> 4, rl7 = rl & 7;
  const int lr = lane >> 3, lc = (lane & 7) ^ (lr & 7);
  const u16* aSrc = Wbf + (size_t)(r0 + wid * 32 + lr) * DDIM + lc * 8;
  const u16* bSrc = Ubf + (size_t)(b0 + wid * 32 + lr) * DDIM + lc * 8;

  f32x4 acc[4][4] = {};
  gemm_pipeline<8, DDIM, DDIM>(aSrc, bSrc, As0, As1, Bl0, Bl1,
                               wid, wr, wc, rl, kg, rl7, acc);

#pragma unroll
  for (int fm = 0; fm < 4; ++fm) {
    int kbase = r0 + wr * 64 + fm * 16 + kg * 4;
    float b4[4];
#pragma unroll
    for (int r = 0; r < 4; ++r) {
      int kk = kbase + r;
      b4[r] = Bsrc[(kk & 255) * 33 + (kk >> 8)];
    }
#pragma unroll
    for (int fn = 0; fn < 4; ++fn) {
      int b = b0 + wc * 64 + fn * 16 + rl;
      u16 o[4];
#pragma unroll
      for (int r = 0; r < 4; ++r) {
        float x = acc[fm][fn][r] + b4[r];
        o[r] = f2bf(1.0f / (1.0f + __expf(-x)));
      }
      u16* dst = Gt + (size_t)b * KP + kbase;
      *(u32*)(dst)     = (u32)o[0] | ((u32)o[1] << 16);
      *(u32*)(dst + 2) = (u32)o[2] | ((u32)o[3] << 16);
    }
  }
}

// ---------------------------------------------------------------------------
// GEMM2: 256x256 tile, 8 waves (2Mx4N, wave-tile 128x64), BK=64, 8-phase
// schedule (T3+T4+T5), K-split 4 (splits {34,34,32,32} K-steps).
// LDS 128KiB: slot(buf,op,half) = ((buf*2+op)*2+half)*8192 u16.
// Stage map per iter (T=2*it): ph1:A0(T+1)->b1 ph2:A1(T+1)->b1
//   ph3:B0(T+2)->b0 ph4:B1(T+2)->b0 ph5:A0(T+2)->b0 ph6:A1(T+2)->b0
//   ph7:B0(T+3)->b1 ph8:B1(T+3)->b1 ; vmcnt(2) at ph4/ph8 only.
// ---------------------------------------------------------------------------
__global__ __launch_bounds__(512, 2) void k_gemm2(
    const u16* __restrict__ xiT, const u16* __restrict__ Gt,
    float* __restrict__ Out, u16* __restrict__ Part) {
  __shared__ u16 lds[65536];
  const int lid = blockIdx.x;
  const int b0 = (lid & 3) * 256;          // 4 b-tiles
  const int ks = (lid >> 2) & 3;           // 4 K-splits
  const int n0 = (lid >> 4) * 256;         // 16 n-tiles
  const int kOff = (ks < 2) ? ks * 2176 : 4352 + (ks - 2) * 2048;
  const int nt = (ks < 2) ? 34 : 32;       // K-steps (even!)

  const int t = threadIdx.x, lane = t & 63, wid = t >> 6;
  const int wr = wid >> 2, wc = wid & 3;   // 2(M) x 4(N) waves
  const int rl = lane & 15, kg = lane >> 4, rl7 = rl & 7;
  const int sr = lane >> 3;                // stage: row within 8-row group
  const int sc = (lane & 7) ^ sr;          // stage: swizzled col-chunk

  const u16* aS = xiT + (size_t)(n0 + wid * 16 + sr) * 256 + kOff + sc * 8;
  const u16* bS = Gt  + (size_t)(b0 + wid * 16 + sr) * KP  + kOff + sc * 8;

  f32x4 acc[8][4] = {};
  bf16x8 af[8], b01[4], b23[4];

  auto stA = [&](int tile, int half, int buf) {
    u16* d = lds + (buf * 4 + half) * 8192 + wid * 1024;
    const u16* s = aS + (size_t)half * 32768 + (size_t)tile * 64;
    gld16(s, d);
    gld16(s + 2048, d + 512);
  };
  auto stB = [&](int tile, int half, int buf) {
    u16* d = lds + (buf * 4 + 2 + half) * 8192 + wid * 1024;
    const u16* s = bS + (size_t)half * 128 * KP + (size_t)tile * 64;
    gld16(s, d);
    gld16(s + (size_t)8 * KP, d + 512);
  };
  auto rdA = [&](int buf, int sub) {
    const u16* p = lds + (buf * 4 + wr) * 8192;
#pragma unroll
    for (int q = 0; q < 4; ++q)
#pragma unroll
      for (int kh = 0; kh < 2; ++kh)
        af[q * 2 + kh] = *(const bf16x8*)
            &p[((sub * 4 + q) * 16 + rl) * 64 + (((kh * 4 + kg) ^ rl7) * 8)];
  };
  auto rdB = [&](int buf, int sub, bf16x8 (&bq)[4]) {
    const u16* p = lds + (buf * 4 + 2 + (wc >> 1)) * 8192;
#pragma unroll
    for (int q = 0; q < 2; ++q)
#pragma unroll
      for (int kh = 0; kh < 2; ++kh)
        bq[q * 2 + kh] = *(const bf16x8*)
            &p[((wc & 1) * 64 + (sub * 2 + q) * 16 + rl) * 64 +
               (((kh * 4 + kg) ^ rl7) * 8)];
  };
  auto mm = [&](int sm, int sn, bf16x8 (&bq)[4]) {
    __builtin_amdgcn_s_setprio(1);
#pragma unroll
    for (int q = 0; q < 4; ++q)
#pragma unroll
      for (int p = 0; p < 2; ++p)
#pragma unroll
        for (int kh = 0; kh < 2; ++kh)
          acc[sm * 4 + q][sn * 2 + p] = __builtin_amdgcn_mfma_f32_16x16x32_bf16(
              af[q * 2 + kh], bq[p * 2 + kh], acc[sm * 4 + q][sn * 2 + p], 0, 0, 0);
    __builtin_amdgcn_s_setprio(0);
  };

  // prologue: T0 complete (buf0) + B-halves of T1 (buf1)
  stA(0, 0, 0); stA(0, 1, 0); stB(0, 0, 0); stB(0, 1, 0);
  stB(1, 0, 1); stB(1, 1, 1);
  WAITVM(4);          // T0's 8 loads landed
  BAR();

  const int nIter = nt >> 1;
#pragma unroll 1
  for (int it = 0; it < nIter; ++it) {
    const int T = it * 2;
    const bool s2 = (T + 2 < nt);
    // ph1: quad(0,0) of T (buf0)
    rdA(0, 0); rdB(0, 0, b01); stA(T + 1, 0, 1);
    BAR(); LGKM0(); mm(0, 0, b01); BAR();
    // ph2: quad(0,1)
    rdB(0, 1, b23); stA(T + 1, 1, 1);
    BAR(); LGKM0(); mm(0, 1, b23); BAR();
    // ph3: quad(1,0)
    rdA(0, 1); if (s2) stB(T + 2, 0, 0);
    BAR(); LGKM0(); mm(1, 0, b01); BAR();
    // ph4: quad(1,1)  [no ds_reads]
    if (s2) { stB(T + 2, 1, 0); WAITVM(2); } else { WAITVM(0); }
    BAR(); mm(1, 1, b23); BAR();
    // ph5: quad(0,0) of T+1 (buf1)
    rdA(1, 0); rdB(1, 0, b01); if (s2) stA(T + 2, 0, 0);
    BAR(); LGKM0(); mm(0, 0, b01); BAR();
    // ph6: quad(0,1)
    rdB(1, 1, b23); if (s2) stA(T + 2, 1, 0);
    BAR(); LGKM0(); mm(0, 1, b23); BAR();
    // ph7: quad(1,0)
    rdA(1, 1); if (s2) stB(T + 3, 0, 1);
    BAR(); LGKM0(); mm(1, 0, b01); BAR();
    // ph8: quad(1,1)
    if (s2) stB(T + 3, 1, 1);
    WAITVM(2);
    BAR(); mm(1, 1, b23); BAR();
  }

  // epilogue
  if (ks == 0) {
#pragma unroll
    for (int fm = 0; fm < 8; ++fm)
#pragma unroll
      for (int fn = 0; fn < 4; ++fn) {
        int n = n0 + wr * 128 + fm * 16 + kg * 4;
        int b = b0 + wc * 64 + fn * 16 + rl;
#pragma unroll
        for (int r = 0; r < 4; ++r)
          Out[(size_t)(n + r) * NB + b] = acc[fm][fn][r];
      }
  } else {
    u16* P = Part + (size_t)(ks - 1) * (NN * NB);
#pragma unroll
    for (int fm = 0; fm < 8; ++fm)
#pragma unroll
      for (int fn = 0; fn < 4; ++fn) {
        int n = n0 + wr * 128 + fm * 16 + kg * 4;
        int b = b0 + wc * 64 + fn * 16 + rl;
#pragma unroll
        for (int r = 0; r < 4; ++r)
          P[(size_t)(n + r) * NB + b] = f2bf(acc[fm][fn][r]);
      }
  }
}

// ---------------------------------------------------------------------------
// Reduce: Out += P0 + P1 + P2  (bf16 partials)
// ---------------------------------------------------------------------------
__global__ __launch_bounds__(256) void k_reduce(float* __restrict__ Out,
                                                const u16* __restrict__ Part) {
  size_t i = (size_t)blockIdx.x * 256 + threadIdx.x;   // float4 index
  float4 a = ((const float4*)Out)[i];
#pragma unroll
  for (int p = 0; p < 3; ++p) {
    ushort4 v = ((const ushort4*)(Part + (size_t)p * (NN * NB)))[i];
    a.x += bf2f(v.x); a.y += bf2f(v.y); a.z += bf2f(v.z); a.w += bf2f(v.w);
  }
  ((float4*)Out)[i] = a;
}

// ---------------------------------------------------------------------------
extern "C" void kernel_launch(void* const* d_in, const int* in_sizes, int n_in,
                              void* d_out, int out_size, void* d_ws, size_t ws_size,
                              hipStream_t stream) {
  const float* u  = (const float*)d_in[0];   // (1024, 512)
  const float* w  = (const float*)d_in[1];   // (256, 33, 512)
  const float* bs = (const float*)d_in[2];   // (256, 33, 1)
  const float* xi = (const float*)d_in[3];   // (256, 4128)
  float* out = (float*)d_out;                // (4096, 1024) f32

  u16* xiT  = (u16*)d_ws;                          //  2,113,536 B
  u16* Gt   = (u16*)((char*)d_ws + 2113536);       // 17,301,504 B
  u16* Wbf  = (u16*)((char*)d_ws + 19415040);      //  8,650,752 B (dead after gemm1)
  u16* Ubf  = (u16*)((char*)d_ws + 28065792);      //  1,048,576 B (dead after gemm1)
  // Part aliases Wbf/Ubf (stream-ordered: gemm2 runs after gemm1): 3x8,388,608 B
  u16* Part = (u16*)((char*)d_ws + 19415040);      // ends at 44,580,864 B

  k_convW<<<8448, 128, 0, stream>>>(w, Wbf);
  k_convU<<<1024, 128, 0, stream>>>(u, Ubf);
  k_transpose_xi<<<dim3(129, 8), 256, 0, stream>>>(xi, xiT);
  k_gemm1<<<dim3(66, 8), 256, 0, stream>>>(Wbf, Ubf, bs, Gt);
  k_gemm2<<<256, 512, 0, stream>>>(xiT, Gt, out, Part);
  k_reduce<<<4096, 256, 0, stream>>>(out, Part);
}

// Round 6
// 107.136 us; speedup vs baseline: 2.6943x; 1.0496x over previous
//
#include <hip/hip_runtime.h>
#include <hip/hip_bf16.h>

typedef __attribute__((ext_vector_type(8))) short bf16x8;
typedef __attribute__((ext_vector_type(4))) float f32x4;
typedef unsigned int u32;
typedef unsigned short u16;

#define XI_ROW 4128   // N + 2L
#define KP     8448   // M * W, k' = j*256 + m
#define NB     1024
#define NN     4096
#define DDIM   512

__device__ __forceinline__ u16 f2bf(float f) {
  union { float f; unsigned u; } c; c.f = f;
  return (u16)((c.u + 0x7FFFu + ((c.u >> 16) & 1u)) >> 16);
}
__device__ __forceinline__ float bf2f(u16 h) {
  union { u32 u; float f; } c; c.u = ((u32)h) << 16; return c.f;
}
__device__ __forceinline__ u32 pk2bf(float a, float b) {
  return (u32)f2bf(a) | ((u32)f2bf(b) << 16);
}
__device__ __forceinline__ void gld16(const u16* g, u16* l) {
  __builtin_amdgcn_global_load_lds(
      (const __attribute__((address_space(1))) u32*)(const void*)g,
      (__attribute__((address_space(3))) u32*)(void*)l, 16, 0, 0);
}

#define BAR() __builtin_amdgcn_s_barrier()
#define LGKM0() asm volatile("s_waitcnt lgkmcnt(0)" ::: "memory")
#define WAITVM(N) asm volatile("s_waitcnt vmcnt(" #N ")" ::: "memory")
#define SCHED0() __builtin_amdgcn_sched_barrier(0)

// ---------------------------------------------------------------------------
// Fused prep: convW (blocks [0,4224)), convU ([4224,4736)), transpose xi
// ([4736,5768)). One launch instead of three.
// ---------------------------------------------------------------------------
__global__ __launch_bounds__(256) void k_prep(
    const float* __restrict__ w, const float* __restrict__ u,
    const float* __restrict__ xi, u16* __restrict__ Wbf,
    u16* __restrict__ Ubf, u16* __restrict__ xiT) {
  __shared__ u16 tile[32][33];
  const int bx = blockIdx.x, t = threadIdx.x;
  if (bx < 4224) {                       // weight f32 -> bf16, k'=j*256+m rows
    int kp = bx * 2 + (t >> 7), tl = t & 127;
    int m = kp & 255, j = kp >> 8;
    float4 v = ((const float4*)(w + (size_t)(m * 33 + j) * DDIM))[tl];
    ((uint2*)(Wbf + (size_t)kp * DDIM))[tl] =
        make_uint2(pk2bf(v.x, v.y), pk2bf(v.z, v.w));
  } else if (bx < 4736) {                // u f32 -> bf16
    int b = (bx - 4224) * 2 + (t >> 7), tl = t & 127;
    float4 v = ((const float4*)(u + (size_t)b * DDIM))[tl];
    ((uint2*)(Ubf + (size_t)b * DDIM))[tl] =
        make_uint2(pk2bf(v.x, v.y), pk2bf(v.z, v.w));
  } else {                               // xi (256x4128) -> xiT (4128x256) bf16
    int bx2 = bx - 4736;
    int cblk = bx2 % 129, mblk = bx2 / 129;
    int c0 = cblk * 32, m0 = mblk * 32;
    int tx = t & 31, ty = t >> 5;
#pragma unroll
    for (int i = 0; i < 4; ++i)
      tile[ty + i * 8][tx] = f2bf(xi[(size_t)(m0 + ty + i * 8) * XI_ROW + c0 + tx]);
    __syncthreads();
#pragma unroll
    for (int i = 0; i < 4; ++i)
      xiT[(size_t)(c0 + ty + i * 8) * 256 + m0 + tx] = tile[tx][ty + i * 8];
  }
}

// ---------------------------------------------------------------------------
// 2-phase pipelined core for GEMM1 (proven): 128x128 tile, 4 waves, BK=64.
// ---------------------------------------------------------------------------
template<int KSTEPS, int AS, int BS>
__device__ __forceinline__ void gemm_pipeline(
    const u16* __restrict__ aSrc, const u16* __restrict__ bSrc,
    u16* As0, u16* As1, u16* Bl0, u16* Bl1,
    int wid, int wr, int wc, int rl, int kg, int rl7,
    f32x4 (&acc)[4][4]) {

  auto stage = [&](u16* Ab, u16* Bb, int kk) {
#pragma unroll
    for (int i = 0; i < 4; ++i)
      gld16(aSrc + (size_t)i * 8 * AS + kk, &Ab[(wid * 4 + i) * 512]);
#pragma unroll
    for (int i = 0; i < 4; ++i)
      gld16(bSrc + (size_t)i * 8 * BS + kk, &Bb[(wid * 4 + i) * 512]);
  };
  auto compute = [&](const u16* Ab, const u16* Bb) {
#pragma unroll
    for (int kh = 0; kh < 2; ++kh) {
      bf16x8 af[4], bfv[4];
#pragma unroll
      for (int fm = 0; fm < 4; ++fm)
        af[fm] = *(const bf16x8*)&Ab[(wr * 64 + fm * 16 + rl) * 64 +
                                     (((kh * 4 + kg) ^ rl7) * 8)];
#pragma unroll
      for (int fn = 0; fn < 4; ++fn)
        bfv[fn] = *(const bf16x8*)&Bb[(wc * 64 + fn * 16 + rl) * 64 +
                                      (((kh * 4 + kg) ^ rl7) * 8)];
      __builtin_amdgcn_s_setprio(1);
#pragma unroll
      for (int fm = 0; fm < 4; ++fm)
#pragma unroll
        for (int fn = 0; fn < 4; ++fn)
          acc[fm][fn] = __builtin_amdgcn_mfma_f32_16x16x32_bf16(
              af[fm], bfv[fn], acc[fm][fn], 0, 0, 0);
      __builtin_amdgcn_s_setprio(0);
    }
  };

  stage(As0, Bl0, 0);
  WAITVM(0);
  BAR();
#pragma unroll 1
  for (int ts = 0; ts < KSTEPS - 2; ts += 2) {
    stage(As1, Bl1, (ts + 1) * 64);
    WAITVM(8);
    BAR();
    compute(As0, Bl0);
    BAR();
    stage(As0, Bl0, (ts + 2) * 64);
    WAITVM(8);
    BAR();
    compute(As1, Bl1);
    BAR();
  }
  stage(As1, Bl1, (KSTEPS - 1) * 64);
  WAITVM(8);
  BAR();
  compute(As0, Bl0);
  BAR();
  WAITVM(0);
  BAR();
  compute(As1, Bl1);
}

// ---------------------------------------------------------------------------
// GEMM1: Gt[b][k'] = sigmoid(Wbf[k',:]·Ubf[b,:] + bias[k'])
// ---------------------------------------------------------------------------
__global__ __launch_bounds__(256) void k_gemm1(
    const u16* __restrict__ Wbf, const u16* __restrict__ Ubf,
    const float* __restrict__ Bsrc, u16* __restrict__ Gt) {
  __shared__ u16 As0[8192], As1[8192], Bl0[8192], Bl1[8192];
  const int r0 = blockIdx.x * 128;
  const int b0 = blockIdx.y * 128;
  const int t = threadIdx.x, lane = t & 63, wid = t >> 6;
  const int wr = wid >> 1, wc = wid & 1;
  const int rl = lane & 15, kg = lane >> 4, rl7 = rl & 7;
  const int lr = lane >> 3, lc = (lane & 7) ^ (lr & 7);
  const u16* aSrc = Wbf + (size_t)(r0 + wid * 32 + lr) * DDIM + lc * 8;
  const u16* bSrc = Ubf + (size_t)(b0 + wid * 32 + lr) * DDIM + lc * 8;

  f32x4 acc[4][4] = {};
  gemm_pipeline<8, DDIM, DDIM>(aSrc, bSrc, As0, As1, Bl0, Bl1,
                               wid, wr, wc, rl, kg, rl7, acc);

#pragma unroll
  for (int fm = 0; fm < 4; ++fm) {
    int kbase = r0 + wr * 64 + fm * 16 + kg * 4;
    float b4[4];
#pragma unroll
    for (int r = 0; r < 4; ++r) {
      int kk = kbase + r;
      b4[r] = Bsrc[(kk & 255) * 33 + (kk >> 8)];
    }
#pragma unroll
    for (int fn = 0; fn < 4; ++fn) {
      int b = b0 + wc * 64 + fn * 16 + rl;
      u16 o[4];
#pragma unroll
      for (int r = 0; r < 4; ++r) {
        float x = acc[fm][fn][r] + b4[r];
        o[r] = f2bf(1.0f / (1.0f + __expf(-x)));
      }
      u16* dst = Gt + (size_t)b * KP + kbase;
      *(u32*)(dst)     = (u32)o[0] | ((u32)o[1] << 16);
      *(u32*)(dst + 2) = (u32)o[2] | ((u32)o[3] << 16);
    }
  }
}

// ---------------------------------------------------------------------------
// GEMM2: 256x256 tile, 8 waves (2Mx4N, wave-tile 128x64), BK=64, 8-phase
// schedule (T3+T4+T5) with sched_barrier-pinned phases, K-split 4.
// LDS 128KiB: slot(buf,op,half) = ((buf*2+op)*2+half)*8192 u16.
// vmcnt(4) at ph4/ph8 = minimal wait (A/B of next-needed tile only).
// ---------------------------------------------------------------------------
__global__ __launch_bounds__(512, 2) void k_gemm2(
    const u16* __restrict__ xiT, const u16* __restrict__ Gt,
    float* __restrict__ Out, u16* __restrict__ Part) {
  __shared__ u16 lds[65536];
  const int lid = blockIdx.x;
  const int b0 = (lid & 3) * 256;          // 4 b-tiles
  const int ks = (lid >> 2) & 3;           // 4 K-splits
  const int n0 = (lid >> 4) * 256;         // 16 n-tiles
  const int kOff = (ks < 2) ? ks * 2176 : 4352 + (ks - 2) * 2048;
  const int nt = (ks < 2) ? 34 : 32;       // K-steps (even)

  const int t = threadIdx.x, lane = t & 63, wid = t >> 6;
  const int wr = wid >> 2, wc = wid & 3;   // 2(M) x 4(N) waves
  const int rl = lane & 15, kg = lane >> 4, rl7 = rl & 7;
  const int sr = lane >> 3;                // stage: row within 8-row group
  const int sc = (lane & 7) ^ sr;          // stage: swizzled col-chunk

  const u16* aS = xiT + (size_t)(n0 + wid * 16 + sr) * 256 + kOff + sc * 8;
  const u16* bS = Gt  + (size_t)(b0 + wid * 16 + sr) * KP  + kOff + sc * 8;

  f32x4 acc[8][4] = {};
  bf16x8 af[8], b01[4], b23[4];

  auto stA = [&](int tile, int half, int buf) {
    u16* d = lds + (buf * 4 + half) * 8192 + wid * 1024;
    const u16* s = aS + (size_t)half * 32768 + (size_t)tile * 64;
    gld16(s, d);
    gld16(s + 2048, d + 512);
  };
  auto stB = [&](int tile, int half, int buf) {
    u16* d = lds + (buf * 4 + 2 + half) * 8192 + wid * 1024;
    const u16* s = bS + (size_t)half * 128 * KP + (size_t)tile * 64;
    gld16(s, d);
    gld16(s + (size_t)8 * KP, d + 512);
  };
  auto rdA = [&](int buf, int sub) {
    const u16* p = lds + (buf * 4 + wr) * 8192;
#pragma unroll
    for (int q = 0; q < 4; ++q)
#pragma unroll
      for (int kh = 0; kh < 2; ++kh)
        af[q * 2 + kh] = *(const bf16x8*)
            &p[((sub * 4 + q) * 16 + rl) * 64 + (((kh * 4 + kg) ^ rl7) * 8)];
  };
  auto rdB = [&](int buf, int sub, bf16x8 (&bq)[4]) {
    const u16* p = lds + (buf * 4 + 2 + (wc >> 1)) * 8192;
#pragma unroll
    for (int q = 0; q < 2; ++q)
#pragma unroll
      for (int kh = 0; kh < 2; ++kh)
        bq[q * 2 + kh] = *(const bf16x8*)
            &p[((wc & 1) * 64 + (sub * 2 + q) * 16 + rl) * 64 +
               (((kh * 4 + kg) ^ rl7) * 8)];
  };
  auto mm = [&](int sm, int sn, bf16x8 (&bq)[4]) {
    __builtin_amdgcn_s_setprio(1);
#pragma unroll
    for (int q = 0; q < 4; ++q)
#pragma unroll
      for (int p = 0; p < 2; ++p)
#pragma unroll
        for (int kh = 0; kh < 2; ++kh)
          acc[sm * 4 + q][sn * 2 + p] = __builtin_amdgcn_mfma_f32_16x16x32_bf16(
              af[q * 2 + kh], bq[p * 2 + kh], acc[sm * 4 + q][sn * 2 + p], 0, 0, 0);
    __builtin_amdgcn_s_setprio(0);
  };

  auto runIter = [&](int T, bool s2) {
    // ph1: quad(0,0) of tile T (buf0)
    rdA(0, 0); rdB(0, 0, b01); stA(T + 1, 0, 1);
    SCHED0(); BAR(); LGKM0(); SCHED0(); mm(0, 0, b01); BAR();
    // ph2: quad(0,1)
    rdB(0, 1, b23); stA(T + 1, 1, 1);
    SCHED0(); BAR(); LGKM0(); SCHED0(); mm(0, 1, b23); BAR();
    // ph3: quad(1,0)
    rdA(0, 1); if (s2) stB(T + 2, 0, 0);
    SCHED0(); BAR(); LGKM0(); SCHED0(); mm(1, 0, b01); BAR();
    // ph4: quad(1,1)  [no ds_reads]
    if (s2) { stB(T + 2, 1, 0); WAITVM(4); } else { WAITVM(0); }
    SCHED0(); BAR(); SCHED0(); mm(1, 1, b23); BAR();
    // ph5: quad(0,0) of tile T+1 (buf1)
    rdA(1, 0); rdB(1, 0, b01); if (s2) stA(T + 2, 0, 0);
    SCHED0(); BAR(); LGKM0(); SCHED0(); mm(0, 0, b01); BAR();
    // ph6: quad(0,1)
    rdB(1, 1, b23); if (s2) stA(T + 2, 1, 0);
    SCHED0(); BAR(); LGKM0(); SCHED0(); mm(0, 1, b23); BAR();
    // ph7: quad(1,0)
    rdA(1, 1); if (s2) stB(T + 3, 0, 1);
    SCHED0(); BAR(); LGKM0(); SCHED0(); mm(1, 0, b01); BAR();
    // ph8: quad(1,1)
    if (s2) { stB(T + 3, 1, 1); WAITVM(4); }
    SCHED0(); BAR(); SCHED0(); mm(1, 1, b23); BAR();
  };

  // prologue: T0 complete (buf0) + B-halves of T1 (buf1)
  stA(0, 0, 0); stA(0, 1, 0); stB(0, 0, 0); stB(0, 1, 0);
  stB(1, 0, 1); stB(1, 1, 1);
  WAITVM(4);          // T0's 8 loads landed; B(1) stays in flight
  BAR();

  const int nIter = nt >> 1;
#pragma unroll 1
  for (int it = 0; it < nIter - 1; ++it) runIter(it * 2, true);
  runIter((nIter - 1) * 2, false);   // peeled tail, branch-free main loop

  // epilogue
  if (ks == 0) {
#pragma unroll
    for (int fm = 0; fm < 8; ++fm)
#pragma unroll
      for (int fn = 0; fn < 4; ++fn) {
        int n = n0 + wr * 128 + fm * 16 + kg * 4;
        int b = b0 + wc * 64 + fn * 16 + rl;
#pragma unroll
        for (int r = 0; r < 4; ++r)
          Out[(size_t)(n + r) * NB + b] = acc[fm][fn][r];
      }
  } else {
    u16* P = Part + (size_t)(ks - 1) * (NN * NB);
#pragma unroll
    for (int fm = 0; fm < 8; ++fm)
#pragma unroll
      for (int fn = 0; fn < 4; ++fn) {
        int n = n0 + wr * 128 + fm * 16 + kg * 4;
        int b = b0 + wc * 64 + fn * 16 + rl;
#pragma unroll
        for (int r = 0; r < 4; ++r)
          P[(size_t)(n + r) * NB + b] = f2bf(acc[fm][fn][r]);
      }
  }
}

// ---------------------------------------------------------------------------
// Reduce: Out += P0 + P1 + P2  (bf16 partials)
// ---------------------------------------------------------------------------
__global__ __launch_bounds__(256) void k_reduce(float* __restrict__ Out,
                                                const u16* __restrict__ Part) {
  size_t i = (size_t)blockIdx.x * 256 + threadIdx.x;   // float4 index
  float4 a = ((const float4*)Out)[i];
#pragma unroll
  for (int p = 0; p < 3; ++p) {
    ushort4 v = ((const ushort4*)(Part + (size_t)p * (NN * NB)))[i];
    a.x += bf2f(v.x); a.y += bf2f(v.y); a.z += bf2f(v.z); a.w += bf2f(v.w);
  }
  ((float4*)Out)[i] = a;
}

// ---------------------------------------------------------------------------
extern "C" void kernel_launch(void* const* d_in, const int* in_sizes, int n_in,
                              void* d_out, int out_size, void* d_ws, size_t ws_size,
                              hipStream_t stream) {
  const float* u  = (const float*)d_in[0];   // (1024, 512)
  const float* w  = (const float*)d_in[1];   // (256, 33, 512)
  const float* bs = (const float*)d_in[2];   // (256, 33, 1)
  const float* xi = (const float*)d_in[3];   // (256, 4128)
  float* out = (float*)d_out;                // (4096, 1024) f32

  u16* xiT  = (u16*)d_ws;                          //  2,113,536 B
  u16* Gt   = (u16*)((char*)d_ws + 2113536);       // 17,301,504 B
  u16* Wbf  = (u16*)((char*)d_ws + 19415040);      //  8,650,752 B (dead after gemm1)
  u16* Ubf  = (u16*)((char*)d_ws + 28065792);      //  1,048,576 B (dead after gemm1)
  // Part aliases Wbf/Ubf (stream-ordered: gemm2 after gemm1): 3x8,388,608 B
  u16* Part = (u16*)((char*)d_ws + 19415040);      // ends at 44,580,864 B

  k_prep<<<5768, 256, 0, stream>>>(w, u, xi, Wbf, Ubf, xiT);
  k_gemm1<<<dim3(66, 8), 256, 0, stream>>>(Wbf, Ubf, bs, Gt);
  k_gemm2<<<256, 512, 0, stream>>>(xiT, Gt, out, Part);
  k_reduce<<<4096, 256, 0, stream>>>(out, Part);
}